// Round 4
// baseline (2412.335 us; speedup 1.0000x reference)
//
#include <hip/hip_runtime.h>
#include <stdint.h>
#include <stddef.h>

// Conv_M: fused dynamic-filter conv. B=4, Cin=Cout=64, H=W=128, K=3.
// R4: k_gemm2 occupancy fix. R3 was latency-bound at 2 waves/SIMD because
// acc[4][8] (128 AGPR) + 128 VGPR hit the 256-reg cap. New shape: 512-thr
// blocks, 8 waves in 2x4 grid, wave tile 64x64 (acc[4][4] = 64 regs) ->
// <=128 total regs, 4 waves/SIMD, 2 blocks/CU, 16 waves/CU. Same o-major
// chunking (chunk = 4 outch x all 64 c) + dbuf single-barrier K-loop.

using short8  = __attribute__((ext_vector_type(8))) short;
using float4v = __attribute__((ext_vector_type(4))) float;

#define DI __device__ __forceinline__

DI unsigned short f2bf(float f) {
  union { float f; unsigned int u; } a; a.f = f;
  unsigned int r = a.u + 0x7fffu + ((a.u >> 16) & 1u);
  return (unsigned short)(r >> 16);
}
DI float bf2f(unsigned short u) {
  union { unsigned int u; float f; } a; a.u = ((unsigned int)u) << 16;
  return a.f;
}
DI void gll16(const void* g, void* l) {
  __builtin_amdgcn_global_load_lds(
      (const __attribute__((address_space(1))) unsigned int*)g,
      (__attribute__((address_space(3))) unsigned int*)l, 16, 0, 0);
}

// 16-lane (l15-group) sum via DPP — VALU pipe, no LDS traffic.
template <int CTRL>
DI float dpp_add(float v) {
  union { float f; int i; } a; a.f = v;
  a.i = __builtin_amdgcn_update_dpp(0, a.i, CTRL, 0xF, 0xF, true);
  return v + a.f;
}
DI float sum16(float v) {
  v = dpp_add<0xB1>(v);   // quad_perm [1,0,3,2]
  v = dpp_add<0x4E>(v);   // quad_perm [2,3,0,1]
  v = dpp_add<0x141>(v);  // row_half_mirror
  v = dpp_add<0x140>(v);  // row_mirror
  return v;
}

// ---------------------------------------------------------------------------
// feat layout: idx = ((kk*512 + pblk)*4 + q)*1024 + plocal*8 + j8
//   kk = k/32 (36 blocks), pblk = pixel/128 (512), q = (k>>3)&3, j8 = k&7.
// feat col = c*9 + (kh*3+kw) for x (cols 0..575), same +576 for m.
// ---------------------------------------------------------------------------
__global__ void k_feat(const float* __restrict__ x, const float* __restrict__ m,
                       unsigned short* __restrict__ featb) {
  unsigned int tid = blockIdx.x * 256u + threadIdx.x;  // < 75,497,472
  int j8   = tid & 7;
  int pl   = (tid >> 3) & 127;
  int q    = (tid >> 10) & 3;
  int pblk = (tid >> 12) & 511;
  int kk   = tid >> 21;
  int col  = kk * 32 + q * 8 + j8;
  const float* src = x;
  int jx = col;
  if (col >= 576) { src = m; jx = col - 576; }
  int c  = jx / 9;
  int t  = jx - c * 9;
  int t3 = t / 3;
  int dh = t3 - 1;
  int dw = (t - t3 * 3) - 1;
  int p  = pblk * 128 + pl;
  int b  = p >> 14, h = (p >> 7) & 127, w = p & 127;
  int hh = min(max(h + dh, 0), 127);   // replicate pad
  int ww = min(max(w + dw, 0), 127);
  featb[tid] = f2bf(src[(((b << 6) | c) << 14) + (hh << 7) + ww]);
}

// Weight swizzle: src row-major [k][n] fp32 -> bf16 B-frag tiles at
//   idx = ((k>>5)*ntiles + (n'>>4))*512 + ((k>>3)&3)*128 + (n'&15)*8 + (k&7)
// perm=1 (W2): n' = (n&63)<<6 | (n>>6)  (o-major: n' = o*64 + c).
__global__ void k_sw(const float* __restrict__ Wsrc, unsigned short* __restrict__ Wdst,
                     int ncols, int ntiles, int total, int perm) {
  int tid = blockIdx.x * 256 + threadIdx.x;
  if (tid >= total) return;
  int k = tid / ncols;
  int n = tid - k * ncols;
  int np = perm ? (((n & 63) << 6) | (n >> 6)) : n;
  int out = ((k >> 5) * ntiles + (np >> 4)) * 512 + ((k >> 3) & 3) * 128 +
            (np & 15) * 8 + (k & 7);
  Wdst[out] = f2bf(Wsrc[tid]);
}

// ---------------------------------------------------------------------------
// GEMM1: w1 = feat@W1 + b1, then yr/mr/sr[p][c] via 3x3 taps on fp32 x/m/s.
// ---------------------------------------------------------------------------
__launch_bounds__(512, 2)
__global__ void k_gemm1(const unsigned short* __restrict__ featb,
                        const unsigned short* __restrict__ W1s,
                        const float* __restrict__ b1,
                        const float* __restrict__ x, const float* __restrict__ m,
                        const float* __restrict__ s,
                        float* __restrict__ yr, float* __restrict__ mr,
                        float* __restrict__ sr) {
  __shared__ __align__(16) unsigned short Alds[4096];       // 8KB  [q][p128][j8]
  __shared__ __align__(16) unsigned short Blds[4608];       // 9216B: 9 tiles
  __shared__ __align__(16) unsigned short w1buf[128 * 152]; // 38912B
  const int tid = threadIdx.x;
  const int wv  = tid >> 6;
  const int l15 = tid & 15;
  const int q   = (tid >> 4) & 3;
  const int bm  = blockIdx.x, nb = blockIdx.y;

  float4v acc[9];
#pragma unroll
  for (int t = 0; t < 9; ++t) acc[t] = (float4v){0.f, 0.f, 0.f, 0.f};

  const unsigned short* Ab = featb + (size_t)bm * 4096;
  const unsigned short* Bb = W1s + (size_t)nb * 9 * 512;

  for (int kk = 0; kk < 36; ++kk) {
    __syncthreads();
    gll16(Ab + (size_t)kk * 2097152 + tid * 8, (char*)Alds + wv * 1024);
    gll16(Bb + (size_t)kk * 18432 + tid * 8, (char*)Blds + wv * 1024);
    if (tid < 64) gll16(Bb + (size_t)kk * 18432 + 4096 + tid * 8, (char*)Blds + 8192);
    __syncthreads();
    short8 af = *(const short8*)&Alds[q * 1024 + (16 * wv + l15) * 8];
#pragma unroll
    for (int t = 0; t < 9; ++t) {
      short8 bfr = *(const short8*)&Blds[t * 512 + q * 128 + l15 * 8];
      acc[t] = __builtin_amdgcn_mfma_f32_16x16x32_bf16(af, bfr, acc[t], 0, 0, 0);
    }
  }

  // w1 (+bias) -> LDS as bf16. C/D layout: col=lane&15, row=quad*4+i.
#pragma unroll
  for (int t = 0; t < 9; ++t) {
    int col = 16 * t + l15;
    float bb = b1[nb * 144 + col];
#pragma unroll
    for (int i = 0; i < 4; ++i) {
      int plr = 16 * wv + 4 * q + i;
      w1buf[plr * 152 + col] = f2bf(acc[t][i] + bb);
    }
  }
  __syncthreads();

  const int b = bm >> 7, h = bm & 127;  // m-block = one (b,h) image row
#pragma unroll
  for (int ii = 0; ii < 4; ++ii) {
    int task = ii * 512 + tid;     // 2048 tasks: (p 0..127) x (cl 0..15)
    int p  = task >> 4;
    int cl = task & 15;
    int c  = nb * 16 + cl;
    float w1v[9];
#pragma unroll
    for (int k = 0; k < 9; ++k) w1v[k] = bf2f(w1buf[p * 152 + cl * 9 + k]);
    size_t base = (size_t)(((b << 6) | c) << 14);
    float vy = 0.f, vm = 0.f, vs = 0.f;
#pragma unroll
    for (int dh = -1; dh <= 1; ++dh) {
      int hh = min(max(h + dh, 0), 127);
#pragma unroll
      for (int dw = -1; dw <= 1; ++dw) {
        int ww = min(max(p + dw, 0), 127);
        size_t idx = base + (hh << 7) + ww;
        int k = (dh + 1) * 3 + (dw + 1);
        float wv1 = w1v[k], aw = fabsf(wv1);
        vy += x[idx] * wv1;
        vm += m[idx] * aw;
        vs += s[idx] * aw;
      }
    }
    size_t P = (size_t)bm * 128 + p;
    yr[P * 64 + c] = vy;
    mr[P * 64 + c] = vm;
    sr[P * 64 + c] = vs;
  }
}

// ---------------------------------------------------------------------------
// GEMM2: block = 128 rows x 256 cols/chunk, 16 chunks (o-major: chunk ch
// covers o in {4ch..4ch+3}, all 64 c). 512 thr = 8 waves in 2x4 grid:
// wm=wv>>2 row group of 64, wn=wv&3 col group of 64. Wave tile 64x64,
// acc[4][4] = 64 regs -> 4 waves/SIMD, 2 blocks/CU. Double-buffered LDS,
// one barrier per K-step. Each wave's 64 cols = one o (=4ch+wn), all 64 c:
// epilogue contracts c in-lane (4 t-terms) + across 16 lanes via DPP.
// ---------------------------------------------------------------------------
__launch_bounds__(512, 4)
__global__ void k_gemm2(const unsigned short* __restrict__ featb,
                        const unsigned short* __restrict__ W2s,
                        const float* __restrict__ b2,
                        const float* __restrict__ yr, const float* __restrict__ mr,
                        const float* __restrict__ sr,
                        float* __restrict__ out) {
  __shared__ __align__(16) unsigned short Alds[2][4096];  // 2 x 8KB
  __shared__ __align__(16) unsigned short Blds[2][8192];  // 2 x 16KB
  const int tid  = threadIdx.x;
  const int wv   = tid >> 6;     // 0..7
  const int wm   = wv >> 2;      // 0..1: 64-row group
  const int wn   = wv & 3;       // 0..3: 64-col group (= one o per chunk)
  const int l15  = tid & 15;
  const int q    = (tid >> 4) & 3;
  const int bm   = blockIdx.x;
  const int b    = bm >> 7, h = bm & 127;

  const unsigned short* Ab = featb + (size_t)bm * 4096;

  float4v acc[4][4];
#pragma unroll
  for (int r = 0; r < 4; ++r)
#pragma unroll
    for (int t = 0; t < 4; ++t) acc[r][t] = (float4v){0.f, 0.f, 0.f, 0.f};

  // prologue: stage (ch=0, kk=0) into buffer 0 (3 gll16 per thread)
  gll16(Ab + tid * 8, (char*)Alds[0] + wv * 1024);
  gll16(W2s + tid * 8, (char*)Blds[0] + wv * 1024);
  gll16(W2s + (512 + tid) * 8, (char*)Blds[0] + 8192 + wv * 1024);

  for (int ch = 0; ch < 16; ++ch) {
    for (int kk = 0; kk < 36; ++kk) {
      __syncthreads();  // buf[kk&1] staged; prior reads of buf[(kk+1)&1] done
      if (!(ch == 15 && kk == 35)) {
        int kkn = (kk == 35) ? 0 : kk + 1;
        int chn = (kk == 35) ? ch + 1 : ch;
        const unsigned short* Ag = Ab + (size_t)kkn * 2097152;
        const unsigned short* Bg = W2s + (size_t)kkn * 131072 + chn * 8192;
        char* Al = (char*)Alds[(kk + 1) & 1];
        char* Bl = (char*)Blds[(kk + 1) & 1];
        gll16(Ag + tid * 8, Al + wv * 1024);
        gll16(Bg + tid * 8, Bl + wv * 1024);
        gll16(Bg + (512 + tid) * 8, Bl + 8192 + wv * 1024);
      }
      const unsigned short* Al = Alds[kk & 1];
      const unsigned short* Bl = Blds[kk & 1];
      short8 a[4];
#pragma unroll
      for (int r = 0; r < 4; ++r)
        a[r] = *(const short8*)&Al[q * 1024 + (64 * wm + 16 * r + l15) * 8];
#pragma unroll
      for (int t = 0; t < 4; ++t) {
        short8 bfr = *(const short8*)&Bl[(4 * wn + t) * 512 + q * 128 + l15 * 8];
#pragma unroll
        for (int r = 0; r < 4; ++r)
          acc[r][t] = __builtin_amdgcn_mfma_f32_16x16x32_bf16(a[r], bfr, acc[r][t], 0, 0, 0);
      }
    }

    // ---- epilogue for chunk ch: this wave's cols n' = 256ch + 64wn + 16t
    //      + l15 -> o = 4ch + wn (uniform per wave), c = 16t + l15. ----
    const int o = 4 * ch + wn;
    float b2v[4];
#pragma unroll
    for (int t = 0; t < 4; ++t) b2v[t] = b2[(16 * t + l15) * 64 + o];
#pragma unroll
    for (int r = 0; r < 4; ++r) {
#pragma unroll
      for (int i = 0; i < 4; ++i) {
        int plr = 64 * wm + 16 * r + 4 * q + i;
        size_t P = (size_t)bm * 128 + plr;
        float ys = 0.f, ms = 0.f, ss = 0.f;
#pragma unroll
        for (int t = 0; t < 4; ++t) {
          float w2f = acc[r][t][i] + b2v[t];
          float aw  = fabsf(w2f);
          ys += yr[P * 64 + 16 * t + l15] * w2f;
          ms += mr[P * 64 + 16 * t + l15] * aw;
          ss += sr[P * 64 + 16 * t + l15] * aw;
        }
        ys = sum16(ys); ms = sum16(ms); ss = sum16(ss);
        if (l15 == 0) {
          size_t idx = ((size_t)((b << 6) | o) << 14) + (h << 7) + plr;
          out[idx]           = ys;
          out[4194304 + idx] = ms / ss;
          out[8388608 + idx] = 1.0f;
        }
      }
    }
    // reset accumulators for next chunk
#pragma unroll
    for (int r = 0; r < 4; ++r)
#pragma unroll
      for (int t = 0; t < 4; ++t) acc[r][t] = (float4v){0.f, 0.f, 0.f, 0.f};
  }
}

// ---------------------------------------------------------------------------
extern "C" void kernel_launch(void* const* d_in, const int* in_sizes, int n_in,
                              void* d_out, int out_size, void* d_ws, size_t ws_size,
                              hipStream_t stream) {
  const float* x  = (const float*)d_in[0];
  const float* m  = (const float*)d_in[1];
  const float* s  = (const float*)d_in[2];
  const float* W1 = (const float*)d_in[3];
  const float* b1 = (const float*)d_in[4];
  const float* W2 = (const float*)d_in[5];
  const float* b2 = (const float*)d_in[6];
  float* out = (float*)d_out;

  // ws layout (bytes):
  //   feat  bf16 : [0, 150994944)               36*65536*32 elems
  //   W1s   bf16 : [150994944, 152322048)       1152*576
  //   W2s   bf16 : [152322048, 161759232)       1152*4096 (o-major permuted)
  //   yr/mr/sr f32: 3 x 16777216 from 161759232 ; end = 212090880
  if (ws_size < 212090880ull) return;
  char* ws = (char*)d_ws;
  unsigned short* featb = (unsigned short*)ws;
  unsigned short* W1s   = (unsigned short*)(ws + 150994944);
  unsigned short* W2s   = (unsigned short*)(ws + 152322048);
  float* yr = (float*)(ws + 161759232);
  float* mr = (float*)(ws + 178536448);
  float* sr = (float*)(ws + 195313664);

  k_feat<<<294912, 256, 0, stream>>>(x, m, featb);
  k_sw<<<2592, 256, 0, stream>>>(W1, W1s, 576, 36, 663552, 0);
  k_sw<<<18432, 256, 0, stream>>>(W2, W2s, 4096, 256, 4718592, 1);
  dim3 g1(512, 4);
  k_gemm1<<<g1, 512, 0, stream>>>(featb, W1s, b1, x, m, s, yr, mr, sr);
  k_gemm2<<<512, 512, 0, stream>>>(featb, W2s, b2, yr, mr, sr, out);
}

// Round 5
// 1430.182 us; speedup vs baseline: 1.6867x; 1.6867x over previous
//
#include <hip/hip_runtime.h>
#include <stdint.h>
#include <stddef.h>

// Conv_M: fused dynamic-filter conv. B=4, Cin=Cout=64, H=W=128, K=3.
// R5: R4's K-loop (o-major chunks, 64x64 wave tiles, acc[4][4]=64 regs,
// dbuf single-barrier staging, 2 blocks/CU) + rebuilt epilogue: per chunk,
// per o-plane, owning waves dump acc(+b2) to LDS w2buf (bf16, padded), then
// all 8 waves split by ROWS (no redundancy) and read yr/mr/sr with float4
// coalesced loads, contract c via in-lane MACs + 2 shfl_xor, store 64B
// coalesced. R4's failure was 3.2 GB of scattered scalar epilogue loads.

using short8   = __attribute__((ext_vector_type(8))) short;
using float4v  = __attribute__((ext_vector_type(4))) float;
using ushort4v = __attribute__((ext_vector_type(4))) unsigned short;

#define DI __device__ __forceinline__

DI unsigned short f2bf(float f) {
  union { float f; unsigned int u; } a; a.f = f;
  unsigned int r = a.u + 0x7fffu + ((a.u >> 16) & 1u);
  return (unsigned short)(r >> 16);
}
DI float bf2f(unsigned short u) {
  union { unsigned int u; float f; } a; a.u = ((unsigned int)u) << 16;
  return a.f;
}
DI void gll16(const void* g, void* l) {
  __builtin_amdgcn_global_load_lds(
      (const __attribute__((address_space(1))) unsigned int*)g,
      (__attribute__((address_space(3))) unsigned int*)l, 16, 0, 0);
}

// ---------------------------------------------------------------------------
// feat layout: idx = ((kk*512 + pblk)*4 + q)*1024 + plocal*8 + j8
//   kk = k/32 (36 blocks), pblk = pixel/128 (512), q = (k>>3)&3, j8 = k&7.
// feat col = c*9 + (kh*3+kw) for x (cols 0..575), same +576 for m.
// ---------------------------------------------------------------------------
__global__ void k_feat(const float* __restrict__ x, const float* __restrict__ m,
                       unsigned short* __restrict__ featb) {
  unsigned int tid = blockIdx.x * 256u + threadIdx.x;  // < 75,497,472
  int j8   = tid & 7;
  int pl   = (tid >> 3) & 127;
  int q    = (tid >> 10) & 3;
  int pblk = (tid >> 12) & 511;
  int kk   = tid >> 21;
  int col  = kk * 32 + q * 8 + j8;
  const float* src = x;
  int jx = col;
  if (col >= 576) { src = m; jx = col - 576; }
  int c  = jx / 9;
  int t  = jx - c * 9;
  int t3 = t / 3;
  int dh = t3 - 1;
  int dw = (t - t3 * 3) - 1;
  int p  = pblk * 128 + pl;
  int b  = p >> 14, h = (p >> 7) & 127, w = p & 127;
  int hh = min(max(h + dh, 0), 127);   // replicate pad
  int ww = min(max(w + dw, 0), 127);
  featb[tid] = f2bf(src[(((b << 6) | c) << 14) + (hh << 7) + ww]);
}

// Weight swizzle: src row-major [k][n] fp32 -> bf16 B-frag tiles at
//   idx = ((k>>5)*ntiles + (n'>>4))*512 + ((k>>3)&3)*128 + (n'&15)*8 + (k&7)
// perm=1 (W2): n' = (n&63)<<6 | (n>>6)  (o-major: n' = o*64 + c).
__global__ void k_sw(const float* __restrict__ Wsrc, unsigned short* __restrict__ Wdst,
                     int ncols, int ntiles, int total, int perm) {
  int tid = blockIdx.x * 256 + threadIdx.x;
  if (tid >= total) return;
  int k = tid / ncols;
  int n = tid - k * ncols;
  int np = perm ? (((n & 63) << 6) | (n >> 6)) : n;
  int out = ((k >> 5) * ntiles + (np >> 4)) * 512 + ((k >> 3) & 3) * 128 +
            (np & 15) * 8 + (k & 7);
  Wdst[out] = f2bf(Wsrc[tid]);
}

// ---------------------------------------------------------------------------
// GEMM1: w1 = feat@W1 + b1, then yr/mr/sr[p][c] via 3x3 taps on fp32 x/m/s.
// ---------------------------------------------------------------------------
__launch_bounds__(512, 2)
__global__ void k_gemm1(const unsigned short* __restrict__ featb,
                        const unsigned short* __restrict__ W1s,
                        const float* __restrict__ b1,
                        const float* __restrict__ x, const float* __restrict__ m,
                        const float* __restrict__ s,
                        float* __restrict__ yr, float* __restrict__ mr,
                        float* __restrict__ sr) {
  __shared__ __align__(16) unsigned short Alds[4096];       // 8KB  [q][p128][j8]
  __shared__ __align__(16) unsigned short Blds[4608];       // 9216B: 9 tiles
  __shared__ __align__(16) unsigned short w1buf[128 * 152]; // 38912B
  const int tid = threadIdx.x;
  const int wv  = tid >> 6;
  const int l15 = tid & 15;
  const int q   = (tid >> 4) & 3;
  const int bm  = blockIdx.x, nb = blockIdx.y;

  float4v acc[9];
#pragma unroll
  for (int t = 0; t < 9; ++t) acc[t] = (float4v){0.f, 0.f, 0.f, 0.f};

  const unsigned short* Ab = featb + (size_t)bm * 4096;
  const unsigned short* Bb = W1s + (size_t)nb * 9 * 512;

  for (int kk = 0; kk < 36; ++kk) {
    __syncthreads();
    gll16(Ab + (size_t)kk * 2097152 + tid * 8, (char*)Alds + wv * 1024);
    gll16(Bb + (size_t)kk * 18432 + tid * 8, (char*)Blds + wv * 1024);
    if (tid < 64) gll16(Bb + (size_t)kk * 18432 + 4096 + tid * 8, (char*)Blds + 8192);
    __syncthreads();
    short8 af = *(const short8*)&Alds[q * 1024 + (16 * wv + l15) * 8];
#pragma unroll
    for (int t = 0; t < 9; ++t) {
      short8 bfr = *(const short8*)&Blds[t * 512 + q * 128 + l15 * 8];
      acc[t] = __builtin_amdgcn_mfma_f32_16x16x32_bf16(af, bfr, acc[t], 0, 0, 0);
    }
  }

  // w1 (+bias) -> LDS as bf16. C/D layout: col=lane&15, row=quad*4+i.
#pragma unroll
  for (int t = 0; t < 9; ++t) {
    int col = 16 * t + l15;
    float bb = b1[nb * 144 + col];
#pragma unroll
    for (int i = 0; i < 4; ++i) {
      int plr = 16 * wv + 4 * q + i;
      w1buf[plr * 152 + col] = f2bf(acc[t][i] + bb);
    }
  }
  __syncthreads();

  const int b = bm >> 7, h = bm & 127;  // m-block = one (b,h) image row
#pragma unroll
  for (int ii = 0; ii < 4; ++ii) {
    int task = ii * 512 + tid;     // 2048 tasks: (p 0..127) x (cl 0..15)
    int p  = task >> 4;
    int cl = task & 15;
    int c  = nb * 16 + cl;
    float w1v[9];
#pragma unroll
    for (int k = 0; k < 9; ++k) w1v[k] = bf2f(w1buf[p * 152 + cl * 9 + k]);
    size_t base = (size_t)(((b << 6) | c) << 14);
    float vy = 0.f, vm = 0.f, vs = 0.f;
#pragma unroll
    for (int dh = -1; dh <= 1; ++dh) {
      int hh = min(max(h + dh, 0), 127);
#pragma unroll
      for (int dw = -1; dw <= 1; ++dw) {
        int ww = min(max(p + dw, 0), 127);
        size_t idx = base + (hh << 7) + ww;
        int k = (dh + 1) * 3 + (dw + 1);
        float wv1 = w1v[k], aw = fabsf(wv1);
        vy += x[idx] * wv1;
        vm += m[idx] * aw;
        vs += s[idx] * aw;
      }
    }
    size_t P = (size_t)bm * 128 + p;
    yr[P * 64 + c] = vy;
    mr[P * 64 + c] = vm;
    sr[P * 64 + c] = vs;
  }
}

// ---------------------------------------------------------------------------
// GEMM2: block = 128 rows x 256 cols/chunk, 16 chunks (o-major: chunk ch
// covers o in {4ch..4ch+3}, all 64 c). 512 thr = 8 waves in 2x4 grid:
// wm=wv>>2 row group of 64, wn=wv&3 -> wave's o = 4ch+wn, c = 16t+l15.
// K-loop: dbuf, one barrier per step, 3 gll16/thread, 16 MFMA/wave/step.
// Epilogue per chunk: 4 o-planes; owning waves (wn==p) write acc+b2 -> LDS
// w2buf bf16 [128][68-pad]; then all waves take 16 DISTINCT rows each,
// lane part=lane>>4 owns a 16-c quarter: float4-coalesced yr/mr/sr loads,
// ds_read_b64 w2 frags, 2x shfl_xor part-reduce, 64B-coalesced stores.
// ---------------------------------------------------------------------------
__launch_bounds__(512, 4)
__global__ void k_gemm2(const unsigned short* __restrict__ featb,
                        const unsigned short* __restrict__ W2s,
                        const float* __restrict__ b2,
                        const float* __restrict__ yr, const float* __restrict__ mr,
                        const float* __restrict__ sr,
                        float* __restrict__ out) {
  __shared__ __align__(16) unsigned short Alds[2][4096];   // 2 x 8KB
  __shared__ __align__(16) unsigned short Blds[2][8192];   // 2 x 16KB
  __shared__ __align__(16) unsigned short w2buf[128 * 68]; // 17408B, padded
  const int tid  = threadIdx.x;
  const int wv   = tid >> 6;     // 0..7
  const int lane = tid & 63;
  const int wm   = wv >> 2;      // 0..1: 64-row group
  const int wn   = wv & 3;       // 0..3: o = 4ch+wn
  const int l15  = tid & 15;
  const int q    = (tid >> 4) & 3;
  const int part = lane >> 4;    // 0..3: 16-c quarter (epilogue)
  const int bm   = blockIdx.x;
  const int b    = bm >> 7, h = bm & 127;

  const unsigned short* Ab = featb + (size_t)bm * 4096;

  float4v acc[4][4];
#pragma unroll
  for (int r = 0; r < 4; ++r)
#pragma unroll
    for (int t = 0; t < 4; ++t) acc[r][t] = (float4v){0.f, 0.f, 0.f, 0.f};

  // prologue: stage (ch=0, kk=0) into buffer 0 (3 gll16 per thread)
  gll16(Ab + tid * 8, (char*)Alds[0] + wv * 1024);
  gll16(W2s + tid * 8, (char*)Blds[0] + wv * 1024);
  gll16(W2s + (512 + tid) * 8, (char*)Blds[0] + 8192 + wv * 1024);

  for (int ch = 0; ch < 16; ++ch) {
    for (int kk = 0; kk < 36; ++kk) {
      __syncthreads();  // buf[kk&1] staged; prior reads of buf[(kk+1)&1] done
      if (!(ch == 15 && kk == 35)) {
        int kkn = (kk == 35) ? 0 : kk + 1;
        int chn = (kk == 35) ? ch + 1 : ch;
        const unsigned short* Ag = Ab + (size_t)kkn * 2097152;
        const unsigned short* Bg = W2s + (size_t)kkn * 131072 + chn * 8192;
        char* Al = (char*)Alds[(kk + 1) & 1];
        char* Bl = (char*)Blds[(kk + 1) & 1];
        gll16(Ag + tid * 8, Al + wv * 1024);
        gll16(Bg + tid * 8, Bl + wv * 1024);
        gll16(Bg + (512 + tid) * 8, Bl + 8192 + wv * 1024);
      }
      const unsigned short* Al = Alds[kk & 1];
      const unsigned short* Bl = Blds[kk & 1];
      short8 a[4];
#pragma unroll
      for (int r = 0; r < 4; ++r)
        a[r] = *(const short8*)&Al[q * 1024 + (64 * wm + 16 * r + l15) * 8];
#pragma unroll
      for (int t = 0; t < 4; ++t) {
        short8 bfr = *(const short8*)&Bl[(4 * wn + t) * 512 + q * 128 + l15 * 8];
#pragma unroll
        for (int r = 0; r < 4; ++r)
          acc[r][t] = __builtin_amdgcn_mfma_f32_16x16x32_bf16(a[r], bfr, acc[r][t], 0, 0, 0);
      }
    }

    // ---- epilogue: 4 o-planes, LDS-redistributed ----
    // this wave's acc: rows 64wm+16r+4q+i, c = 16t+l15, o = 4ch+wn.
    float b2v[4];
#pragma unroll
    for (int t = 0; t < 4; ++t) b2v[t] = b2[(16 * t + l15) * 64 + 4 * ch + wn];

    for (int p = 0; p < 4; ++p) {
      __syncthreads();           // w2buf free (K-loop done / prior reads done)
      if (wn == p) {
#pragma unroll
        for (int r = 0; r < 4; ++r)
#pragma unroll
          for (int t = 0; t < 4; ++t)
#pragma unroll
            for (int i = 0; i < 4; ++i)
              w2buf[(64 * wm + 16 * r + 4 * q + i) * 68 + 16 * t + l15] =
                  f2bf(acc[r][t][i] + b2v[t]);
      }
      __syncthreads();
      // all waves: row = 16wv + l15 (distinct rows per wave), quarter = part
      const int row = 16 * wv + l15;
      const size_t P = (size_t)bm * 128 + row;
      const float4v* y4 = (const float4v*)(yr + P * 64 + 16 * part);
      const float4v* m4 = (const float4v*)(mr + P * 64 + 16 * part);
      const float4v* s4 = (const float4v*)(sr + P * 64 + 16 * part);
      const ushort4v* w4 = (const ushort4v*)&w2buf[row * 68 + 16 * part];
      float ys = 0.f, ms = 0.f, ss = 0.f;
#pragma unroll
      for (int j4 = 0; j4 < 4; ++j4) {
        float4v yv = y4[j4], mv = m4[j4], sv = s4[j4];
        ushort4v wq = w4[j4];
#pragma unroll
        for (int j = 0; j < 4; ++j) {
          float w2f = bf2f(wq[j]);
          float aw  = fabsf(w2f);
          ys += yv[j] * w2f;
          ms += mv[j] * aw;
          ss += sv[j] * aw;
        }
      }
      ys += __shfl_xor(ys, 16); ys += __shfl_xor(ys, 32);
      ms += __shfl_xor(ms, 16); ms += __shfl_xor(ms, 32);
      ss += __shfl_xor(ss, 16); ss += __shfl_xor(ss, 32);
      if (part == 0) {
        const int o = 4 * ch + p;
        size_t idx = ((size_t)((b << 6) | o) << 14) + (h << 7) + row;
        out[idx]           = ys;
        out[4194304 + idx] = ms / ss;
        out[8388608 + idx] = 1.0f;
      }
    }
    // reset accumulators for next chunk
#pragma unroll
    for (int r = 0; r < 4; ++r)
#pragma unroll
      for (int t = 0; t < 4; ++t) acc[r][t] = (float4v){0.f, 0.f, 0.f, 0.f};
  }
}

// ---------------------------------------------------------------------------
extern "C" void kernel_launch(void* const* d_in, const int* in_sizes, int n_in,
                              void* d_out, int out_size, void* d_ws, size_t ws_size,
                              hipStream_t stream) {
  const float* x  = (const float*)d_in[0];
  const float* m  = (const float*)d_in[1];
  const float* s  = (const float*)d_in[2];
  const float* W1 = (const float*)d_in[3];
  const float* b1 = (const float*)d_in[4];
  const float* W2 = (const float*)d_in[5];
  const float* b2 = (const float*)d_in[6];
  float* out = (float*)d_out;

  // ws layout (bytes):
  //   feat  bf16 : [0, 150994944)               36*65536*32 elems
  //   W1s   bf16 : [150994944, 152322048)       1152*576
  //   W2s   bf16 : [152322048, 161759232)       1152*4096 (o-major permuted)
  //   yr/mr/sr f32: 3 x 16777216 from 161759232 ; end = 212090880
  if (ws_size < 212090880ull) return;
  char* ws = (char*)d_ws;
  unsigned short* featb = (unsigned short*)ws;
  unsigned short* W1s   = (unsigned short*)(ws + 150994944);
  unsigned short* W2s   = (unsigned short*)(ws + 152322048);
  float* yr = (float*)(ws + 161759232);
  float* mr = (float*)(ws + 178536448);
  float* sr = (float*)(ws + 195313664);

  k_feat<<<294912, 256, 0, stream>>>(x, m, featb);
  k_sw<<<2592, 256, 0, stream>>>(W1, W1s, 576, 36, 663552, 0);
  k_sw<<<18432, 256, 0, stream>>>(W2, W2s, 4096, 256, 4718592, 1);
  dim3 g1(512, 4);
  k_gemm1<<<g1, 512, 0, stream>>>(featb, W1s, b1, x, m, s, yr, mr, sr);
  k_gemm2<<<512, 512, 0, stream>>>(featb, W2s, b2, yr, mr, sr, out);
}